// Round 10
// baseline (151.157 us; speedup 1.0000x reference)
//
#include <hip/hip_runtime.h>

// GAT layer N=50000, E=800000, DIN=DOUT=128, H=4.
// ALGEBRAIC SIMPLIFICATION: per-(node,head) softmax weights sum to exactly 1,
// so attn_w[n,h] = 1/deg[n] and
//   out[n] = (deg[n]>0) ? (1/deg[n]) * sum_{e:col=n} v[row[e]] : 0,
//   v = x @ Wv^T + bv.
// Wq,bq,Wk,bk,att do not affect the output.
//
// R3 lesson: no LDS atomics in the per-edge-per-channel path (662us disaster).
// R4 lesson: scatter is latency-bound -> needs many in-flight blocks.
// R8 lesson: accumulate bf16 in DOUBLE -> exact, order-independent,
//   bit-deterministic under nondeterministic atomic claim order (tripwire).
// R9: gemm+scatter fused. R10: gather reads 4 rows/instruction (16-lane uint4
//   groups), 16 edges in flight; SPAN=64 (782 blocks -> ~24 waves/CU).

#define N_NODES 50000
#define N_EDGES 800000
#define SPAN    64                    // nodes per bucket
#define NBUCK   782                   // ceil(50000/64)
#define CAP     1536                  // per-bucket cap; mean 1024, sd ~32 (fixed input, +16sd)
#define EPB     2048                  // edges per scatter block
#define NCHUNK  391                   // ceil(800000/2048)
#define GEMMB   391                   // gemm blocks (128 nodes each)

// ---- workspace layout (bytes) ----
// vh     : uint[50000*64]    @ 0            (12,800,000)  bf16x2-packed v
// sorted : uint[782*1536]    @ 12,800,000   (4,804,608)   (col<<16)|row, bucket-grouped
// Cursor : int[782]          @ 17,604,608   (zeroed each call)
#define OFF_SORTED 12800000
#define OFF_CURSOR 17604608

typedef __attribute__((ext_vector_type(8))) short short8;
typedef __attribute__((ext_vector_type(4))) float f32x4;

__device__ __forceinline__ unsigned int pack_bf16_rne(float a, float b) {
    unsigned int ua = __float_as_uint(a), ub = __float_as_uint(b);
    unsigned int ha = (ua + 0x7FFFu + ((ua >> 16) & 1u)) >> 16;
    unsigned int hb = (ub + 0x7FFFu + ((ub >> 16) & 1u)) >> 16;
    return ha | (hb << 16);
}
__device__ __forceinline__ unsigned short bf16_rne(float a) {
    unsigned int ua = __float_as_uint(a);
    return (unsigned short)((ua + 0x7FFFu + ((ua >> 16) & 1u)) >> 16);
}
__device__ __forceinline__ float bflo(unsigned int u) { return __uint_as_float(u << 16); }
__device__ __forceinline__ float bfhi(unsigned int u) { return __uint_as_float(u & 0xFFFF0000u); }

// Fused kernel: blocks [0,390] = gemm (v = x @ Wv^T + bv, MFMA bf16, packed
// bf16 out), blocks [391,781] = scatter chunks. Data-independent halves;
// co-residency hides scatter's memory latency under gemm's MFMA/VALU work.
// LDS manually overlaid (34.8 KB max).
__global__ __launch_bounds__(512) void fused_gemm_scatter(
        const float* __restrict__ x, const float* __restrict__ Wv,
        const float* __restrict__ bv, unsigned int* __restrict__ vh,
        const int* __restrict__ ei, int* __restrict__ Cursor,
        unsigned int* __restrict__ sorted) {
    __shared__ __align__(16) unsigned char smem[128 * 68 * 4];  // 34816 B overlay
    __shared__ int s_wide;
    int t = threadIdx.x;

    if (blockIdx.x < GEMMB) {
        // ---------------- GEMM half ----------------
        unsigned int* wB = (unsigned int*)smem;      // [128][68]
        for (int q = t; q < 8192; q += 512) {        // stage Wv -> bf16 LDS
            int o = q >> 6, k2 = q & 63;
            float2 wp = ((const float2*)Wv)[q];      // Wv[o][2*k2 .. +1]
            wB[o * 68 + k2] = pack_bf16_rne(wp.x, wp.y);
        }
        __syncthreads();

        int lane = t & 63, w = t >> 6;
        int quad = lane >> 4, lc = lane & 15;
        int n0 = blockIdx.x * 128 + w * 16;

        int arow = n0 + lc;
        int arowc = min(arow, N_NODES - 1);          // clamp; stores are guarded
        const float4* xrow = (const float4*)(x + (size_t)arowc * 128);

        f32x4 acc[8];
        #pragma unroll
        for (int ot = 0; ot < 8; ++ot) acc[ot] = (f32x4){0.f, 0.f, 0.f, 0.f};

        #pragma unroll
        for (int ks = 0; ks < 4; ++ks) {
            // A[m=lc][k=ks*32+quad*8+j], j=0..7 -> bf16x8
            float4 f0 = xrow[ks * 8 + quad * 2];
            float4 f1 = xrow[ks * 8 + quad * 2 + 1];
            uint4 a4;
            a4.x = pack_bf16_rne(f0.x, f0.y);
            a4.y = pack_bf16_rne(f0.z, f0.w);
            a4.z = pack_bf16_rne(f1.x, f1.y);
            a4.w = pack_bf16_rne(f1.z, f1.w);
            short8 af = *(const short8*)&a4;
            #pragma unroll
            for (int ot = 0; ot < 8; ++ot) {
                uint4 b4 = *(const uint4*)&wB[(ot * 16 + lc) * 68 + ks * 16 + quad * 4];
                short8 bf = *(const short8*)&b4;
                acc[ot] = __builtin_amdgcn_mfma_f32_16x16x32_bf16(af, bf, acc[ot], 0, 0, 0);
            }
        }

        // C/D: col = lane&15 (-> o), row = quad*4 + reg (-> node). Pack pairs
        // across lane^1 so even lanes issue 4B stores.
        #pragma unroll
        for (int ot = 0; ot < 8; ++ot) {
            int o = ot * 16 + lc;
            float bb = bv[o];
            #pragma unroll
            for (int r = 0; r < 4; ++r) {
                int node = n0 + quad * 4 + r;
                unsigned short u = bf16_rne(acc[ot][r] + bb);
                unsigned int partner = (unsigned int)__shfl_xor((int)u, 1, 64);
                if ((lane & 1) == 0 && node < N_NODES) {
                    unsigned int pair = (unsigned int)u | (partner << 16);
                    vh[(size_t)node * 64 + (o >> 1)] = pair;
                }
            }
        }
    } else {
        // ---------------- SCATTER half ----------------
        // Bucket counting-sort, fixed per-bucket capacity. Edges cached packed
        // in LDS between count and write passes; per-(block,bin) runs claimed
        // with ONE global atomic so writes merge in L2. Bucket CONTENT is a
        // deterministic multiset; order is not (gather is immune via f64).
        unsigned int* w = (unsigned int*)smem;                    // [EPB] 8192 B
        int* h    = (int*)(smem + EPB * 4);                       // [NBUCK]
        int* base = (int*)(smem + EPB * 4 + NBUCK * 4);           // [NBUCK]
        for (int j = t; j < NBUCK; j += 512) h[j] = 0;
        if (t < 64) {                                // inline dtype detect (wave 0)
            int nz = (ei[2 * t + 1] != 0) ? 1 : 0;   // int64 <=> all high dwords 0
            unsigned long long b = __ballot(nz);
            if (t == 0) s_wide = (b == 0ULL) ? 1 : 0;
        }
        __syncthreads();
        int wide = s_wide;
        int e0 = (blockIdx.x - GEMMB) * EPB;

        #pragma unroll
        for (int k = 0; k < EPB / 512; ++k) {        // pass A: load + count
            int e = e0 + k * 512 + t;
            if (e < N_EDGES) {
                int r, c;
                if (wide) {                          // coalesced 8B loads
                    r = (int)((const uint2*)ei)[e].x;
                    c = (int)((const uint2*)ei)[N_EDGES + e].x;
                } else {
                    r = ei[e];
                    c = ei[N_EDGES + e];
                }
                w[k * 512 + t] = ((unsigned int)c << 16) | (unsigned int)r;
                atomicAdd(&h[c / SPAN], 1);
            } else {
                w[k * 512 + t] = 0xFFFFFFFFu;        // c=65535 never occurs
            }
        }
        __syncthreads();
        for (int j = t; j < NBUCK; j += 512) {       // claim contiguous runs
            int cnt = h[j];
            base[j] = cnt ? atomicAdd(&Cursor[j], cnt) : 0;
            h[j] = 0;                                // reuse as within-block rank
        }
        __syncthreads();
        #pragma unroll
        for (int k = 0; k < EPB / 512; ++k) {        // pass B: ranked write
            unsigned int ww = w[k * 512 + t];
            if (ww != 0xFFFFFFFFu) {
                int bin = (int)(ww >> 16) / SPAN;
                int p = base[bin] + atomicAdd(&h[bin], 1);
                if (p < CAP)                         // overflow guard (never hits)
                    sorted[(size_t)bin * CAP + p] = ww;
            }
        }
    }
}

// One block (512 thr, 8 waves) per bucket; 782 blocks, ~10 KB LDS -> 3
// blocks/CU resident (~24 waves/CU). Local CSR built with cheap int LDS
// atomics (NOT in the per-channel path). Each wave splits into 4 quarter-
// groups of 16 lanes; a quarter reads one full 256B v-row as uint4/lane, so
// ONE instruction covers 4 edges; 4 loads in flight = 16 edges. Quarter sums
// combined via shfl_xor(16/32). ACCUMULATION IN DOUBLE: bf16 sums exactly in
// f64 -> order-independent -> bit-deterministic despite nondeterministic
// bucket order.
__global__ __launch_bounds__(512) void gather_kernel(const unsigned int* __restrict__ vh,
                                                     const unsigned int* __restrict__ sorted,
                                                     const int* __restrict__ Cursor,
                                                     float* __restrict__ out) {
    __shared__ unsigned int ww[CAP];
    __shared__ unsigned short rl[CAP];
    __shared__ int deg[SPAN];
    __shared__ int startc[SPAN];
    __shared__ int curp[SPAN];
    __shared__ int sc_s[SPAN];
    int t = threadIdx.x;
    int b = blockIdx.x;
    int nb0 = b * SPAN;
    int span = min(SPAN, N_NODES - nb0);
    int cnt = min(Cursor[b], CAP);
    if (t < SPAN) deg[t] = 0;
    __syncthreads();

    const unsigned int* run = sorted + (size_t)b * CAP;
    for (int i = t; i < cnt; i += 512) {             // read run once; count
        unsigned int v = run[i];
        ww[i] = v;
        atomicAdd(&deg[(int)(v >> 16) - nb0], 1);
    }
    __syncthreads();

    // exclusive scan of deg[0..63] (Hillis-Steele over 64 slots)
    if (t < SPAN) sc_s[t] = deg[t];
    __syncthreads();
    for (int off = 1; off < SPAN; off <<= 1) {
        int y = (t < SPAN && t >= off) ? sc_s[t - off] : 0;
        __syncthreads();
        if (t < SPAN) sc_s[t] += y;
        __syncthreads();
    }
    if (t < SPAN) { startc[t] = sc_s[t] - deg[t]; curp[t] = 0; }
    __syncthreads();

    for (int i = t; i < cnt; i += 512) {             // rank into local CSR
        unsigned int v = ww[i];
        int ln = (int)(v >> 16) - nb0;
        int p = startc[ln] + atomicAdd(&curp[ln], 1);
        rl[p] = (unsigned short)(v & 0xFFFFu);
    }
    __syncthreads();

    int lane = t & 63, wid = t >> 6;                 // 8 waves, 8 nodes each
    int qg = lane >> 4;                              // quarter group = edge slot
    int li = lane & 15;                              // uint4 index within row
    const uint4* v4 = (const uint4*)vh;              // row = 16 uint4

    for (int ln = wid; ln < span; ln += 8) {
        int s0 = startc[ln], d = deg[ln];
        double c0 = 0., c1 = 0., c2 = 0., c3 = 0.;
        double c4 = 0., c5 = 0., c6 = 0., c7 = 0.;
        int j = 0;
        for (; j + 16 <= d; j += 16) {               // 4 loads = 16 edges in flight
            int r0 = rl[s0 + j + qg];
            int r1 = rl[s0 + j + 4 + qg];
            int r2 = rl[s0 + j + 8 + qg];
            int r3 = rl[s0 + j + 12 + qg];
            uint4 p0 = v4[(size_t)r0 * 16 + li];
            uint4 p1 = v4[(size_t)r1 * 16 + li];
            uint4 p2 = v4[(size_t)r2 * 16 + li];
            uint4 p3 = v4[(size_t)r3 * 16 + li];
            c0 += (double)bflo(p0.x); c1 += (double)bfhi(p0.x);
            c2 += (double)bflo(p0.y); c3 += (double)bfhi(p0.y);
            c4 += (double)bflo(p0.z); c5 += (double)bfhi(p0.z);
            c6 += (double)bflo(p0.w); c7 += (double)bfhi(p0.w);
            c0 += (double)bflo(p1.x); c1 += (double)bfhi(p1.x);
            c2 += (double)bflo(p1.y); c3 += (double)bfhi(p1.y);
            c4 += (double)bflo(p1.z); c5 += (double)bfhi(p1.z);
            c6 += (double)bflo(p1.w); c7 += (double)bfhi(p1.w);
            c0 += (double)bflo(p2.x); c1 += (double)bfhi(p2.x);
            c2 += (double)bflo(p2.y); c3 += (double)bfhi(p2.y);
            c4 += (double)bflo(p2.z); c5 += (double)bfhi(p2.z);
            c6 += (double)bflo(p2.w); c7 += (double)bfhi(p2.w);
            c0 += (double)bflo(p3.x); c1 += (double)bfhi(p3.x);
            c2 += (double)bflo(p3.y); c3 += (double)bfhi(p3.y);
            c4 += (double)bflo(p3.z); c5 += (double)bfhi(p3.z);
            c6 += (double)bflo(p3.w); c7 += (double)bfhi(p3.w);
        }
        for (; j + 4 <= d; j += 4) {                 // 1 load = 4 edges
            int r0 = rl[s0 + j + qg];
            uint4 p0 = v4[(size_t)r0 * 16 + li];
            c0 += (double)bflo(p0.x); c1 += (double)bfhi(p0.x);
            c2 += (double)bflo(p0.y); c3 += (double)bfhi(p0.y);
            c4 += (double)bflo(p0.z); c5 += (double)bfhi(p0.z);
            c6 += (double)bflo(p0.w); c7 += (double)bfhi(p0.w);
        }
        if (j < d) {                                 // ragged 1..3: quarter-predicated
            int idx = j + qg;
            if (idx < d) {
                uint4 p0 = v4[(size_t)rl[s0 + idx] * 16 + li];
                c0 += (double)bflo(p0.x); c1 += (double)bfhi(p0.x);
                c2 += (double)bflo(p0.y); c3 += (double)bfhi(p0.y);
                c4 += (double)bflo(p0.z); c5 += (double)bfhi(p0.z);
                c6 += (double)bflo(p0.w); c7 += (double)bfhi(p0.w);
            }
        }
        // combine the 4 quarter-groups (exact f64 adds)
        c0 += __shfl_xor(c0, 16, 64); c0 += __shfl_xor(c0, 32, 64);
        c1 += __shfl_xor(c1, 16, 64); c1 += __shfl_xor(c1, 32, 64);
        c2 += __shfl_xor(c2, 16, 64); c2 += __shfl_xor(c2, 32, 64);
        c3 += __shfl_xor(c3, 16, 64); c3 += __shfl_xor(c3, 32, 64);
        c4 += __shfl_xor(c4, 16, 64); c4 += __shfl_xor(c4, 32, 64);
        c5 += __shfl_xor(c5, 16, 64); c5 += __shfl_xor(c5, 32, 64);
        c6 += __shfl_xor(c6, 16, 64); c6 += __shfl_xor(c6, 32, 64);
        c7 += __shfl_xor(c7, 16, 64); c7 += __shfl_xor(c7, 32, 64);
        if (qg < 2) {                                // 32 lanes write 512B coalesced
            double sc = (d > 0) ? 1.0 / (double)d : 0.0;
            float4 res;
            if (qg == 0) res = (float4){(float)(c0 * sc), (float)(c1 * sc),
                                        (float)(c2 * sc), (float)(c3 * sc)};
            else         res = (float4){(float)(c4 * sc), (float)(c5 * sc),
                                        (float)(c6 * sc), (float)(c7 * sc)};
            *(float4*)(out + (size_t)(nb0 + ln) * 128 + li * 8 + qg * 4) = res;
        }
    }
}

extern "C" void kernel_launch(void* const* d_in, const int* in_sizes, int n_in,
                              void* d_out, int out_size, void* d_ws, size_t ws_size,
                              hipStream_t stream) {
    const float* x  = (const float*)d_in[0];
    const int*   ei = (const int*)d_in[1];
    const float* Wv = (const float*)d_in[6];
    const float* bv = (const float*)d_in[7];
    float* out = (float*)d_out;

    char* ws = (char*)d_ws;
    unsigned int* vh     = (unsigned int*)(ws);
    unsigned int* sorted = (unsigned int*)(ws + OFF_SORTED);
    int*          Cursor = (int*)(ws + OFF_CURSOR);

    // ws re-poisoned to 0xAA every timed call -> re-zero Cursor each call.
    hipMemsetAsync(Cursor, 0, NBUCK * sizeof(int), stream);
    fused_gemm_scatter<<<GEMMB + NCHUNK, 512, 0, stream>>>(x, Wv, bv, vh,
                                                           ei, Cursor, sorted);
    gather_kernel<<<NBUCK, 512, 0, stream>>>(vh, sorted, Cursor, out);
}

// Round 11
// 149.686 us; speedup vs baseline: 1.0098x; 1.0098x over previous
//
#include <hip/hip_runtime.h>

// GAT layer N=50000, E=800000, DIN=DOUT=128, H=4.
// ALGEBRAIC SIMPLIFICATION: per-(node,head) softmax weights sum to exactly 1,
// so attn_w[n,h] = 1/deg[n] and
//   out[n] = (deg[n]>0) ? (1/deg[n]) * sum_{e:col=n} v[row[e]] : 0,
//   v = x @ Wv^T + bv.
// Wq,bq,Wk,bk,att do not affect the output.
//
// R3 lesson: no LDS atomics in the per-edge-per-channel path (662us disaster).
// R4 lesson: scatter alone is latency-bound; fused with gemm it hides.
// R8 lesson: accumulate bf16 in DOUBLE -> exact, order-independent,
//   bit-deterministic under nondeterministic atomic claim order (tripwire).
// R10 lesson: gather is request-path-bound (~17.8M random 256B rows/ms);
//   occupancy x2 and ILP x8 changes were neutral. SPAN=96 is the sweet spot.
// R11: scatter EPB=4096/196 blocks -> 7.9-entry runs (write-amp ~1.7x vs 6x),
//   ~100K claim atomics (vs 283K).

#define N_NODES 50000
#define N_EDGES 800000
#define SPAN    96                    // nodes per bucket
#define NBUCK   521                   // ceil(50000/96)
#define CAP     2304                  // per-bucket cap; mean 1536, sd ~39 (fixed input, +19sd)
#define EPB     4096                  // edges per scatter block
#define NCHUNK  196                   // ceil(800000/4096)
#define GEMMB   391                   // gemm blocks (128 nodes each)

// ---- workspace layout (bytes) ----
// vh     : uint[50000*64]    @ 0            (12,800,000)  bf16x2-packed v
// sorted : uint[521*2304]    @ 12,800,000   (4,801,536)   (col<<16)|row, bucket-grouped
// Cursor : int[521]          @ 17,601,536   (zeroed each call)
#define OFF_SORTED 12800000
#define OFF_CURSOR 17601536

typedef __attribute__((ext_vector_type(8))) short short8;
typedef __attribute__((ext_vector_type(4))) float f32x4;

__device__ __forceinline__ unsigned int pack_bf16_rne(float a, float b) {
    unsigned int ua = __float_as_uint(a), ub = __float_as_uint(b);
    unsigned int ha = (ua + 0x7FFFu + ((ua >> 16) & 1u)) >> 16;
    unsigned int hb = (ub + 0x7FFFu + ((ub >> 16) & 1u)) >> 16;
    return ha | (hb << 16);
}
__device__ __forceinline__ unsigned short bf16_rne(float a) {
    unsigned int ua = __float_as_uint(a);
    return (unsigned short)((ua + 0x7FFFu + ((ua >> 16) & 1u)) >> 16);
}
__device__ __forceinline__ float bflo(unsigned int u) { return __uint_as_float(u << 16); }
__device__ __forceinline__ float bfhi(unsigned int u) { return __uint_as_float(u & 0xFFFF0000u); }

// Fused kernel: blocks [0,390] = gemm (v = x @ Wv^T + bv, MFMA bf16, packed
// bf16 out), blocks [391,586] = scatter chunks. Data-independent halves;
// co-residency hides scatter's memory latency under gemm's MFMA/VALU work.
// LDS manually overlaid (34.8 KB max -> 4 blocks/CU at 512 thr).
__global__ __launch_bounds__(512) void fused_gemm_scatter(
        const float* __restrict__ x, const float* __restrict__ Wv,
        const float* __restrict__ bv, unsigned int* __restrict__ vh,
        const int* __restrict__ ei, int* __restrict__ Cursor,
        unsigned int* __restrict__ sorted) {
    __shared__ __align__(16) unsigned char smem[128 * 68 * 4];  // 34816 B overlay
    __shared__ int s_wide;
    int t = threadIdx.x;

    if (blockIdx.x < GEMMB) {
        // ---------------- GEMM half ----------------
        unsigned int* wB = (unsigned int*)smem;      // [128][68]
        for (int q = t; q < 8192; q += 512) {        // stage Wv -> bf16 LDS
            int o = q >> 6, k2 = q & 63;
            float2 wp = ((const float2*)Wv)[q];      // Wv[o][2*k2 .. +1]
            wB[o * 68 + k2] = pack_bf16_rne(wp.x, wp.y);
        }
        __syncthreads();

        int lane = t & 63, w = t >> 6;
        int quad = lane >> 4, lc = lane & 15;
        int n0 = blockIdx.x * 128 + w * 16;

        int arow = n0 + lc;
        int arowc = min(arow, N_NODES - 1);          // clamp; stores are guarded
        const float4* xrow = (const float4*)(x + (size_t)arowc * 128);

        f32x4 acc[8];
        #pragma unroll
        for (int ot = 0; ot < 8; ++ot) acc[ot] = (f32x4){0.f, 0.f, 0.f, 0.f};

        #pragma unroll
        for (int ks = 0; ks < 4; ++ks) {
            // A[m=lc][k=ks*32+quad*8+j], j=0..7 -> bf16x8
            float4 f0 = xrow[ks * 8 + quad * 2];
            float4 f1 = xrow[ks * 8 + quad * 2 + 1];
            uint4 a4;
            a4.x = pack_bf16_rne(f0.x, f0.y);
            a4.y = pack_bf16_rne(f0.z, f0.w);
            a4.z = pack_bf16_rne(f1.x, f1.y);
            a4.w = pack_bf16_rne(f1.z, f1.w);
            short8 af = *(const short8*)&a4;
            #pragma unroll
            for (int ot = 0; ot < 8; ++ot) {
                uint4 b4 = *(const uint4*)&wB[(ot * 16 + lc) * 68 + ks * 16 + quad * 4];
                short8 bf = *(const short8*)&b4;
                acc[ot] = __builtin_amdgcn_mfma_f32_16x16x32_bf16(af, bf, acc[ot], 0, 0, 0);
            }
        }

        // C/D: col = lane&15 (-> o), row = quad*4 + reg (-> node). Pack pairs
        // across lane^1 so even lanes issue 4B stores.
        #pragma unroll
        for (int ot = 0; ot < 8; ++ot) {
            int o = ot * 16 + lc;
            float bb = bv[o];
            #pragma unroll
            for (int r = 0; r < 4; ++r) {
                int node = n0 + quad * 4 + r;
                unsigned short u = bf16_rne(acc[ot][r] + bb);
                unsigned int partner = (unsigned int)__shfl_xor((int)u, 1, 64);
                if ((lane & 1) == 0 && node < N_NODES) {
                    unsigned int pair = (unsigned int)u | (partner << 16);
                    vh[(size_t)node * 64 + (o >> 1)] = pair;
                }
            }
        }
    } else {
        // ---------------- SCATTER half ----------------
        // Bucket counting-sort, fixed per-bucket capacity. Edges cached packed
        // in LDS between count and write passes; per-(block,bin) runs claimed
        // with ONE global atomic so writes merge in L2. Bucket CONTENT is a
        // deterministic multiset; order is not (gather is immune via f64).
        unsigned int* w = (unsigned int*)smem;                    // [EPB] 16384 B
        int* h    = (int*)(smem + EPB * 4);                       // [NBUCK]
        int* base = (int*)(smem + EPB * 4 + NBUCK * 4);           // [NBUCK]
        for (int j = t; j < NBUCK; j += 512) h[j] = 0;
        if (t < 64) {                                // inline dtype detect (wave 0)
            int nz = (ei[2 * t + 1] != 0) ? 1 : 0;   // int64 <=> all high dwords 0
            unsigned long long b = __ballot(nz);
            if (t == 0) s_wide = (b == 0ULL) ? 1 : 0;
        }
        __syncthreads();
        int wide = s_wide;
        int e0 = (blockIdx.x - GEMMB) * EPB;

        #pragma unroll
        for (int k = 0; k < EPB / 512; ++k) {        // pass A: load + count
            int e = e0 + k * 512 + t;
            if (e < N_EDGES) {
                int r, c;
                if (wide) {                          // coalesced 8B loads
                    r = (int)((const uint2*)ei)[e].x;
                    c = (int)((const uint2*)ei)[N_EDGES + e].x;
                } else {
                    r = ei[e];
                    c = ei[N_EDGES + e];
                }
                w[k * 512 + t] = ((unsigned int)c << 16) | (unsigned int)r;
                atomicAdd(&h[c / SPAN], 1);
            } else {
                w[k * 512 + t] = 0xFFFFFFFFu;        // c=65535 never occurs
            }
        }
        __syncthreads();
        for (int j = t; j < NBUCK; j += 512) {       // claim contiguous runs
            int cnt = h[j];
            base[j] = cnt ? atomicAdd(&Cursor[j], cnt) : 0;
            h[j] = 0;                                // reuse as within-block rank
        }
        __syncthreads();
        #pragma unroll
        for (int k = 0; k < EPB / 512; ++k) {        // pass B: ranked write
            unsigned int ww = w[k * 512 + t];
            if (ww != 0xFFFFFFFFu) {
                int bin = (int)(ww >> 16) / SPAN;
                int p = base[bin] + atomicAdd(&h[bin], 1);
                if (p < CAP)                         // overflow guard (never hits)
                    sorted[(size_t)bin * CAP + p] = ww;
            }
        }
    }
}

// One block (512 thr, 8 waves) per bucket; 521 blocks, ~15 KB LDS. Local CSR
// built with cheap int LDS atomics (NOT in the per-channel path). Each wave
// splits into 4 quarter-groups of 16 lanes; a quarter reads one full 256B
// v-row as uint4/lane, so ONE instruction covers 4 edges; 4 loads in flight
// = 16 edges. Quarter sums combined via shfl_xor(16/32). ACCUMULATION IN
// DOUBLE: bf16 sums exactly in f64 -> order-independent -> bit-deterministic
// despite nondeterministic bucket order. Measured plateau: ~44.3us
// (request-path-bound, ~17.8M random 256B rows/ms; occupancy/ILP-insensitive).
__global__ __launch_bounds__(512) void gather_kernel(const unsigned int* __restrict__ vh,
                                                     const unsigned int* __restrict__ sorted,
                                                     const int* __restrict__ Cursor,
                                                     float* __restrict__ out) {
    __shared__ unsigned int ww[CAP];
    __shared__ unsigned short rl[CAP];
    __shared__ int deg[SPAN];
    __shared__ int startc[SPAN];
    __shared__ int curp[SPAN];
    __shared__ int sc_s[128];
    int t = threadIdx.x;
    int b = blockIdx.x;
    int nb0 = b * SPAN;
    int span = min(SPAN, N_NODES - nb0);
    int cnt = min(Cursor[b], CAP);
    if (t < SPAN) deg[t] = 0;
    __syncthreads();

    const unsigned int* run = sorted + (size_t)b * CAP;
    for (int i = t; i < cnt; i += 512) {             // read run once; count
        unsigned int v = run[i];
        ww[i] = v;
        atomicAdd(&deg[(int)(v >> 16) - nb0], 1);
    }
    __syncthreads();

    // exclusive scan of deg[0..95] (Hillis-Steele over 128 slots)
    if (t < 128) sc_s[t] = (t < SPAN) ? deg[t] : 0;
    __syncthreads();
    for (int off = 1; off < 128; off <<= 1) {
        int y = (t < 128 && t >= off) ? sc_s[t - off] : 0;
        __syncthreads();
        if (t < 128) sc_s[t] += y;
        __syncthreads();
    }
    if (t < SPAN) { startc[t] = sc_s[t] - deg[t]; curp[t] = 0; }
    __syncthreads();

    for (int i = t; i < cnt; i += 512) {             // rank into local CSR
        unsigned int v = ww[i];
        int ln = (int)(v >> 16) - nb0;
        int p = startc[ln] + atomicAdd(&curp[ln], 1);
        rl[p] = (unsigned short)(v & 0xFFFFu);
    }
    __syncthreads();

    int lane = t & 63, wid = t >> 6;                 // 8 waves, 12 nodes each
    int qg = lane >> 4;                              // quarter group = edge slot
    int li = lane & 15;                              // uint4 index within row
    const uint4* v4 = (const uint4*)vh;              // row = 16 uint4

    for (int ln = wid; ln < span; ln += 8) {
        int s0 = startc[ln], d = deg[ln];
        double c0 = 0., c1 = 0., c2 = 0., c3 = 0.;
        double c4 = 0., c5 = 0., c6 = 0., c7 = 0.;
        int j = 0;
        for (; j + 16 <= d; j += 16) {               // 4 loads = 16 edges in flight
            int r0 = rl[s0 + j + qg];
            int r1 = rl[s0 + j + 4 + qg];
            int r2 = rl[s0 + j + 8 + qg];
            int r3 = rl[s0 + j + 12 + qg];
            uint4 p0 = v4[(size_t)r0 * 16 + li];
            uint4 p1 = v4[(size_t)r1 * 16 + li];
            uint4 p2 = v4[(size_t)r2 * 16 + li];
            uint4 p3 = v4[(size_t)r3 * 16 + li];
            c0 += (double)bflo(p0.x); c1 += (double)bfhi(p0.x);
            c2 += (double)bflo(p0.y); c3 += (double)bfhi(p0.y);
            c4 += (double)bflo(p0.z); c5 += (double)bfhi(p0.z);
            c6 += (double)bflo(p0.w); c7 += (double)bfhi(p0.w);
            c0 += (double)bflo(p1.x); c1 += (double)bfhi(p1.x);
            c2 += (double)bflo(p1.y); c3 += (double)bfhi(p1.y);
            c4 += (double)bflo(p1.z); c5 += (double)bfhi(p1.z);
            c6 += (double)bflo(p1.w); c7 += (double)bfhi(p1.w);
            c0 += (double)bflo(p2.x); c1 += (double)bfhi(p2.x);
            c2 += (double)bflo(p2.y); c3 += (double)bfhi(p2.y);
            c4 += (double)bflo(p2.z); c5 += (double)bfhi(p2.z);
            c6 += (double)bflo(p2.w); c7 += (double)bfhi(p2.w);
            c0 += (double)bflo(p3.x); c1 += (double)bfhi(p3.x);
            c2 += (double)bflo(p3.y); c3 += (double)bfhi(p3.y);
            c4 += (double)bflo(p3.z); c5 += (double)bfhi(p3.z);
            c6 += (double)bflo(p3.w); c7 += (double)bfhi(p3.w);
        }
        for (; j + 4 <= d; j += 4) {                 // 1 load = 4 edges
            int r0 = rl[s0 + j + qg];
            uint4 p0 = v4[(size_t)r0 * 16 + li];
            c0 += (double)bflo(p0.x); c1 += (double)bfhi(p0.x);
            c2 += (double)bflo(p0.y); c3 += (double)bfhi(p0.y);
            c4 += (double)bflo(p0.z); c5 += (double)bfhi(p0.z);
            c6 += (double)bflo(p0.w); c7 += (double)bfhi(p0.w);
        }
        if (j < d) {                                 // ragged 1..3: quarter-predicated
            int idx = j + qg;
            if (idx < d) {
                uint4 p0 = v4[(size_t)rl[s0 + idx] * 16 + li];
                c0 += (double)bflo(p0.x); c1 += (double)bfhi(p0.x);
                c2 += (double)bflo(p0.y); c3 += (double)bfhi(p0.y);
                c4 += (double)bflo(p0.z); c5 += (double)bfhi(p0.z);
                c6 += (double)bflo(p0.w); c7 += (double)bfhi(p0.w);
            }
        }
        // combine the 4 quarter-groups (exact f64 adds)
        c0 += __shfl_xor(c0, 16, 64); c0 += __shfl_xor(c0, 32, 64);
        c1 += __shfl_xor(c1, 16, 64); c1 += __shfl_xor(c1, 32, 64);
        c2 += __shfl_xor(c2, 16, 64); c2 += __shfl_xor(c2, 32, 64);
        c3 += __shfl_xor(c3, 16, 64); c3 += __shfl_xor(c3, 32, 64);
        c4 += __shfl_xor(c4, 16, 64); c4 += __shfl_xor(c4, 32, 64);
        c5 += __shfl_xor(c5, 16, 64); c5 += __shfl_xor(c5, 32, 64);
        c6 += __shfl_xor(c6, 16, 64); c6 += __shfl_xor(c6, 32, 64);
        c7 += __shfl_xor(c7, 16, 64); c7 += __shfl_xor(c7, 32, 64);
        if (qg < 2) {                                // 32 lanes write 512B coalesced
            double sc = (d > 0) ? 1.0 / (double)d : 0.0;
            float4 res;
            if (qg == 0) res = (float4){(float)(c0 * sc), (float)(c1 * sc),
                                        (float)(c2 * sc), (float)(c3 * sc)};
            else         res = (float4){(float)(c4 * sc), (float)(c5 * sc),
                                        (float)(c6 * sc), (float)(c7 * sc)};
            *(float4*)(out + (size_t)(nb0 + ln) * 128 + li * 8 + qg * 4) = res;
        }
    }
}

extern "C" void kernel_launch(void* const* d_in, const int* in_sizes, int n_in,
                              void* d_out, int out_size, void* d_ws, size_t ws_size,
                              hipStream_t stream) {
    const float* x  = (const float*)d_in[0];
    const int*   ei = (const int*)d_in[1];
    const float* Wv = (const float*)d_in[6];
    const float* bv = (const float*)d_in[7];
    float* out = (float*)d_out;

    char* ws = (char*)d_ws;
    unsigned int* vh     = (unsigned int*)(ws);
    unsigned int* sorted = (unsigned int*)(ws + OFF_SORTED);
    int*          Cursor = (int*)(ws + OFF_CURSOR);

    // ws re-poisoned to 0xAA every timed call -> re-zero Cursor each call.
    hipMemsetAsync(Cursor, 0, NBUCK * sizeof(int), stream);
    fused_gemm_scatter<<<GEMMB + NCHUNK, 512, 0, stream>>>(x, Wv, bv, vh,
                                                           ei, Cursor, sorted);
    gather_kernel<<<NBUCK, 512, 0, stream>>>(vh, sorted, Cursor, out);
}